// Round 13
// baseline (316.655 us; speedup 1.0000x reference)
//
#include <hip/hip_runtime.h>
#include <hip/hip_bf16.h>
#include <hip/hip_fp16.h>
#include <cstddef>
#include <cstdint>

#define T_ 4
#define B_ 16
#define N_ 512
#define C_ 512
#define H_ 8
#define D_ 64
#define BN_T (B_*N_)   // 8192

typedef unsigned short u16;
typedef __attribute__((ext_vector_type(8))) short bf16x8;       // 8 bf16
typedef __attribute__((ext_vector_type(8))) _Float16 f16x8;     // 8 fp16
typedef __attribute__((ext_vector_type(8))) unsigned short u16x8;
typedef __attribute__((ext_vector_type(4))) float f32x4;
typedef __attribute__((ext_vector_type(16))) float f32x16;

__device__ __forceinline__ u16 f2bf_exact(float f) {
    union { float f; unsigned u; } x; x.f = f; return (u16)(x.u >> 16);
}
// 2-term exact fp16 split: f == h1 + h2/2048 + tail(<=2^-22|f|)
__device__ __forceinline__ void split2(float f, u16& h1, u16& h2) {
    const __half a = __float2half(f);                   // RNE
    const float r = (f - __half2float(a)) * 2048.0f;    // exact (Sterbenz + pow2)
    const __half b = __float2half(r);
    h1 = __half_as_ushort(a); h2 = __half_as_ushort(b);
}
// XOR swizzle, 16B granularity, BYTE offset into a [128][32] fp16 tile (64B rows)
__device__ __forceinline__ int swz(int rr, int q) {
    return (rr << 6) + (((q ^ ((rr >> 1) & 3)) & 3) << 4);
}
// attention LDS swizzle (element index into [64][64] u16 tiles)
__device__ __forceinline__ int SW(int row, int col) {
    return (row << 6) + (col ^ ((row & 7) << 3));
}
// async global->LDS, 16B per lane (dest = uniform base + lane*16)
__device__ __forceinline__ void gload16(const void* g, void* l) {
    __builtin_amdgcn_global_load_lds(
        (const __attribute__((address_space(1))) unsigned int*)g,
        (__attribute__((address_space(3))) unsigned int*)l, 16, 0, 0);
}

// ---------------------------------------------------------------------------
// x fp32 [T,BN,C] -> tile-major pre-swizzled fp16 splits x1t, x2t.
// ---------------------------------------------------------------------------
__global__ __launch_bounds__(256) void k_split_x(
    const float* __restrict__ x, u16* __restrict__ x1t, u16* __restrict__ x2t)
{
    const int tile = blockIdx.x;            // mt*16 + kb  (4096 tiles)
    const int mt = tile >> 4, kb = tile & 15;
    const int tid = threadIdx.x;
    const int rr = tid >> 1, kh = tid & 1;
    const int t = rr & 3, bn = mt * 32 + (rr >> 2);
    const float* src = x + ((size_t)t * BN_T + bn) * C_ + kb * 32 + kh * 16;
    float f[16];
    *reinterpret_cast<float4*>(f + 0)  = *reinterpret_cast<const float4*>(src + 0);
    *reinterpret_cast<float4*>(f + 4)  = *reinterpret_cast<const float4*>(src + 4);
    *reinterpret_cast<float4*>(f + 8)  = *reinterpret_cast<const float4*>(src + 8);
    *reinterpret_cast<float4*>(f + 12) = *reinterpret_cast<const float4*>(src + 12);
    char* d1 = (char*)(x1t + ((size_t)tile << 12));
    char* d2 = (char*)(x2t + ((size_t)tile << 12));
    #pragma unroll
    for (int j = 0; j < 2; ++j) {
        u16x8 p1, p2;
        #pragma unroll
        for (int e = 0; e < 8; ++e) { u16 h1, h2; split2(f[8*j+e], h1, h2); p1[e] = h1; p2[e] = h2; }
        const int q = 2 * kh + j;
        *reinterpret_cast<u16x8*>(d1 + swz(rr, q)) = p1;
        *reinterpret_cast<u16x8*>(d2 + swz(rr, q)) = p2;
    }
}

// w fp32 [512][512] -> tile-major pre-swizzled fp16 splits
__global__ __launch_bounds__(256) void k_split_w(
    const float* __restrict__ w, u16* __restrict__ w1t, u16* __restrict__ w2t)
{
    const int tile = blockIdx.x;            // nt*16 + kb  (64 tiles)
    const int nt = tile >> 4, kb = tile & 15;
    const int tid = threadIdx.x;
    const int rr = tid >> 1, kh = tid & 1;
    const int c = nt * 128 + rr;
    const float* src = w + (size_t)c * C_ + kb * 32 + kh * 16;
    float f[16];
    *reinterpret_cast<float4*>(f + 0)  = *reinterpret_cast<const float4*>(src + 0);
    *reinterpret_cast<float4*>(f + 4)  = *reinterpret_cast<const float4*>(src + 4);
    *reinterpret_cast<float4*>(f + 8)  = *reinterpret_cast<const float4*>(src + 8);
    *reinterpret_cast<float4*>(f + 12) = *reinterpret_cast<const float4*>(src + 12);
    char* d1 = (char*)(w1t + ((size_t)tile << 12));
    char* d2 = (char*)(w2t + ((size_t)tile << 12));
    #pragma unroll
    for (int j = 0; j < 2; ++j) {
        u16x8 p1, p2;
        #pragma unroll
        for (int e = 0; e < 8; ++e) { u16 h1, h2; split2(f[8*j+e], h1, h2); p1[e] = h1; p2[e] = h2; }
        const int q = 2 * kh + j;
        *reinterpret_cast<u16x8*>(d1 + swz(rr, q)) = p1;
        *reinterpret_cast<u16x8*>(d2 + swz(rr, q)) = p2;
    }
}

// ---------------------------------------------------------------------------
// Merged Q/K/V split-fp16 MFMA Linear -> BN -> LIF(v_th=1) over T=4.
// Round-12 shell (2-buffer, __syncthreads, stage-before-compute, 2x2 waves,
// 128x128 tile) with 32x32x16 MFMAs: 24 MFMA/K-step (vs 48 of 16x16x32),
// same LDS traffic, +15% matrix-pipe cycle efficiency.
// Fragment layouts: A row=lane&31, k=8*(lane>>5)+i; B col=lane&31 same k;
// C/D col=lane&31, row=(p&3)+8*(p>>2)+4*(lane>>5) (m74/m101-verified).
// Rows rr=4*bn_local+t  =>  t == p&3: LIF runs across regs p=4q+t in-lane.
// ---------------------------------------------------------------------------
__global__ __launch_bounds__(256, 2) void k_linear_qkv(
    const u16* __restrict__ a1t, const u16* __restrict__ a2t,
    const u16* __restrict__ wt_base,
    const float* __restrict__ bi0, const float* __restrict__ ga0, const float* __restrict__ be0,
    const float* __restrict__ mu0, const float* __restrict__ va0,
    const float* __restrict__ bi1, const float* __restrict__ ga1, const float* __restrict__ be1,
    const float* __restrict__ mu1, const float* __restrict__ va1,
    const float* __restrict__ bi2, const float* __restrict__ ga2, const float* __restrict__ be2,
    const float* __restrict__ mu2, const float* __restrict__ va2,
    u16* __restrict__ oq, u16* __restrict__ ok, u16* __restrict__ ov)
{
    __shared__ u16 lds[2][4][4096];   // [buf][A1,A2,B1,B2][8KB tile] = 64KB

    const int dd  = blockIdx.x;                    // 0..3071
    const int lid = (dd & 7) * 384 + (dd >> 3);    // XCD swizzle (bijective)
    const int mt  = lid / 12;                      // 0..255
    const int ntg = lid - mt * 12;                 // 0..11
    const int li  = ntg >> 2;                      // which linear 0..2
    const int nt  = ntg & 3;
    const int bn0 = mt * 32;
    const int c0  = nt * 128;

    const float* bias  = li == 0 ? bi0 : li == 1 ? bi1 : bi2;
    const float* gamma = li == 0 ? ga0 : li == 1 ? ga1 : ga2;
    const float* beta  = li == 0 ? be0 : li == 1 ? be1 : be2;
    const float* mean  = li == 0 ? mu0 : li == 1 ? mu1 : mu2;
    const float* var   = li == 0 ? va0 : li == 1 ? va1 : va2;
    u16* outp = li == 0 ? oq : li == 1 ? ok : ov;

    const size_t WSZ = (size_t)C_ * C_;
    const u16* w1t = wt_base + (size_t)(2 * li) * WSZ;
    const u16* w2t = wt_base + (size_t)(2 * li + 1) * WSZ;

    const int tid = threadIdx.x;
    const int wv  = tid >> 6, lane = tid & 63;
    const int l31 = lane & 31, hi = lane >> 5;
    const int wr  = wv >> 1, wc = wv & 1;          // 2x2 wave grid, wave 64x64
    const int go  = wv * 2048 + lane * 16;
    const int lo  = wv * 2048;

    f32x16 accA[2][2], accB[2][2];
    #pragma unroll
    for (int rt2 = 0; rt2 < 2; ++rt2)
        #pragma unroll
        for (int ct2 = 0; ct2 < 2; ++ct2) {
            #pragma unroll
            for (int p = 0; p < 16; ++p) { accA[rt2][ct2][p] = 0.f; accB[rt2][ct2][p] = 0.f; }
        }

    const size_t abase = (size_t)mt * 16, bbase = (size_t)nt * 16;

    auto stage = [&](int buf, int kb) {            // 8 gload16 / thread
        char* L = (char*)&lds[buf][0][0];
        const char* ga1p = (const char*)(a1t + ((abase + kb) << 12)) + go;
        const char* ga2p = (const char*)(a2t + ((abase + kb) << 12)) + go;
        const char* gb1 = (const char*)(w1t + ((bbase + kb) << 12)) + go;
        const char* gb2 = (const char*)(w2t + ((bbase + kb) << 12)) + go;
        gload16(ga1p,        L + lo);
        gload16(ga1p + 1024, L + lo + 1024);
        gload16(ga2p,        L + 8192 + lo);
        gload16(ga2p + 1024, L + 8192 + lo + 1024);
        gload16(gb1,        L + 16384 + lo);
        gload16(gb1 + 1024, L + 16384 + lo + 1024);
        gload16(gb2,        L + 24576 + lo);
        gload16(gb2 + 1024, L + 24576 + lo + 1024);
    };

    stage(0, 0);
    __syncthreads();

    #pragma unroll 1
    for (int kb = 0; kb < 16; ++kb) {
        const int buf = kb & 1;
        if (kb < 15) stage(buf ^ 1, kb + 1);       // async, flies under MFMAs
        const char* L = (const char*)&lds[buf][0][0];
        f16x8 a1[2][2], a2[2][2];
        #pragma unroll
        for (int rt2 = 0; rt2 < 2; ++rt2)
            #pragma unroll
            for (int kh = 0; kh < 2; ++kh) {
                const int rr = 64 * wr + 32 * rt2 + l31;
                const int q = 2 * kh + hi;         // k = 16*kh + 8*hi + i
                a1[rt2][kh] = *reinterpret_cast<const f16x8*>(L + swz(rr, q));
                a2[rt2][kh] = *reinterpret_cast<const f16x8*>(L + 8192 + swz(rr, q));
            }
        #pragma unroll
        for (int ct2 = 0; ct2 < 2; ++ct2) {
            f16x8 b1[2], b2[2];
            #pragma unroll
            for (int kh = 0; kh < 2; ++kh) {
                const int rrB = 64 * wc + 32 * ct2 + l31;
                const int q = 2 * kh + hi;
                b1[kh] = *reinterpret_cast<const f16x8*>(L + 16384 + swz(rrB, q));
                b2[kh] = *reinterpret_cast<const f16x8*>(L + 24576 + swz(rrB, q));
            }
            #pragma unroll
            for (int rt2 = 0; rt2 < 2; ++rt2)
                #pragma unroll
                for (int kh = 0; kh < 2; ++kh) {
                    accA[rt2][ct2] = __builtin_amdgcn_mfma_f32_32x32x16_f16(a1[rt2][kh], b1[kh], accA[rt2][ct2], 0, 0, 0);
                    accB[rt2][ct2] = __builtin_amdgcn_mfma_f32_32x32x16_f16(a2[rt2][kh], b1[kh], accB[rt2][ct2], 0, 0, 0);
                    accB[rt2][ct2] = __builtin_amdgcn_mfma_f32_32x32x16_f16(a1[rt2][kh], b2[kh], accB[rt2][ct2], 0, 0, 0);
                }
        }
        __syncthreads();   // drains stage loads + everyone's reads
    }

    // epilogue: reconstruct -> bias -> BN -> LIF(v_th=1) over reg p=4q+t
    #pragma unroll
    for (int ct2 = 0; ct2 < 2; ++ct2) {
        const int c = c0 + 64 * wc + 32 * ct2 + l31;
        const float rs = 1.0f / sqrtf(var[c] + 1e-5f);
        const float ga = gamma[c], be = beta[c], mu = mean[c], bi = bias[c];
        const int hh = c >> 6, d2 = c & 63;
        #pragma unroll
        for (int rt2 = 0; rt2 < 2; ++rt2) {
            #pragma unroll
            for (int q = 0; q < 4; ++q) {
                const int bn = bn0 + 16 * wr + 8 * rt2 + 2 * q + hi;
                const int b = bn >> 9, n = bn & 511;
                float vm = 0.f;
                #pragma unroll
                for (int t = 0; t < 4; ++t) {
                    const int p = 4 * q + t;
                    const float y = accA[rt2][ct2][p] + accB[rt2][ct2][p] * (1.0f / 2048.0f) + bi;
                    const float ybn = (y - mu) * rs * ga + be;
                    const float h = vm + (ybn - vm) * 0.5f;
                    const bool sp = (h >= 1.0f);
                    vm = sp ? 0.f : h;
                    outp[((((size_t)t * B_ + b) * H_ + hh) * N_ + n) * D_ + d2] = sp ? 0x3F80 : 0;
                }
            }
        }
    }
}

// ---------------------------------------------------------------------------
// Final split-fp16 MFMA Linear (spike fp16 input, 2 terms) -> BN -> LIF,
// fp32 0/1 out. Same shell as k_linear_qkv (128x128 tile, 2x2 waves,
// 2-buffer, 32x32x16 MFMAs, 16/K-step). Units A1,B1,B2 -> 48KB LDS.
// ---------------------------------------------------------------------------
__global__ __launch_bounds__(256, 2) void k_linear_out(
    const u16* __restrict__ a1t,
    const u16* __restrict__ w1t, const u16* __restrict__ w2t,
    const float* __restrict__ bias, const float* __restrict__ gamma,
    const float* __restrict__ beta, const float* __restrict__ mean,
    const float* __restrict__ var, float* __restrict__ outp)
{
    __shared__ u16 lds[2][3][4096];   // [buf][A1,B1,B2] = 48KB

    const int dd  = blockIdx.x;                   // 0..1023
    const int lid = (dd & 7) * 128 + (dd >> 3);   // XCD swizzle (bijective)
    const int mt  = lid >> 2;                     // 0..255
    const int nt  = lid & 3;
    const int bn0 = mt * 32;
    const int c0  = nt * 128;

    const int tid = threadIdx.x;
    const int wv  = tid >> 6, lane = tid & 63;
    const int l31 = lane & 31, hi = lane >> 5;
    const int wr  = wv >> 1, wc = wv & 1;
    const int go  = wv * 2048 + lane * 16;
    const int lo  = wv * 2048;

    f32x16 accA[2][2], accB[2][2];
    #pragma unroll
    for (int rt2 = 0; rt2 < 2; ++rt2)
        #pragma unroll
        for (int ct2 = 0; ct2 < 2; ++ct2) {
            #pragma unroll
            for (int p = 0; p < 16; ++p) { accA[rt2][ct2][p] = 0.f; accB[rt2][ct2][p] = 0.f; }
        }

    const size_t abase = (size_t)mt * 16, bbase = (size_t)nt * 16;

    auto stage = [&](int buf, int kb) {           // 6 gload16 / thread
        char* L = (char*)&lds[buf][0][0];
        const char* ga1 = (const char*)(a1t + ((abase + kb) << 12)) + go;
        const char* gb1 = (const char*)(w1t + ((bbase + kb) << 12)) + go;
        const char* gb2 = (const char*)(w2t + ((bbase + kb) << 12)) + go;
        gload16(ga1,        L + lo);
        gload16(ga1 + 1024, L + lo + 1024);
        gload16(gb1,        L + 8192 + lo);
        gload16(gb1 + 1024, L + 8192 + lo + 1024);
        gload16(gb2,        L + 16384 + lo);
        gload16(gb2 + 1024, L + 16384 + lo + 1024);
    };

    stage(0, 0);
    __syncthreads();

    #pragma unroll 1
    for (int kb = 0; kb < 16; ++kb) {
        const int buf = kb & 1;
        if (kb < 15) stage(buf ^ 1, kb + 1);
        const char* L = (const char*)&lds[buf][0][0];
        f16x8 a1[2][2];
        #pragma unroll
        for (int rt2 = 0; rt2 < 2; ++rt2)
            #pragma unroll
            for (int kh = 0; kh < 2; ++kh) {
                const int rr = 64 * wr + 32 * rt2 + l31;
                const int q = 2 * kh + hi;
                a1[rt2][kh] = *reinterpret_cast<const f16x8*>(L + swz(rr, q));
            }
        #pragma unroll
        for (int ct2 = 0; ct2 < 2; ++ct2) {
            f16x8 b1[2], b2[2];
            #pragma unroll
            for (int kh = 0; kh < 2; ++kh) {
                const int rrB = 64 * wc + 32 * ct2 + l31;
                const int q = 2 * kh + hi;
                b1[kh] = *reinterpret_cast<const f16x8*>(L + 8192 + swz(rrB, q));
                b2[kh] = *reinterpret_cast<const f16x8*>(L + 16384 + swz(rrB, q));
            }
            #pragma unroll
            for (int rt2 = 0; rt2 < 2; ++rt2)
                #pragma unroll
                for (int kh = 0; kh < 2; ++kh) {
                    accA[rt2][ct2] = __builtin_amdgcn_mfma_f32_32x32x16_f16(a1[rt2][kh], b1[kh], accA[rt2][ct2], 0, 0, 0);
                    accB[rt2][ct2] = __builtin_amdgcn_mfma_f32_32x32x16_f16(a1[rt2][kh], b2[kh], accB[rt2][ct2], 0, 0, 0);
                }
        }
        __syncthreads();
    }

    #pragma unroll
    for (int ct2 = 0; ct2 < 2; ++ct2) {
        const int c = c0 + 64 * wc + 32 * ct2 + l31;
        const float rs = 1.0f / sqrtf(var[c] + 1e-5f);
        const float ga = gamma[c], be = beta[c], mu = mean[c], bi = bias[c];
        #pragma unroll
        for (int rt2 = 0; rt2 < 2; ++rt2) {
            #pragma unroll
            for (int q = 0; q < 4; ++q) {
                const int bn = bn0 + 16 * wr + 8 * rt2 + 2 * q + hi;
                float vm = 0.f;
                #pragma unroll
                for (int t = 0; t < 4; ++t) {
                    const int p = 4 * q + t;
                    const float y = accA[rt2][ct2][p] + accB[rt2][ct2][p] * (1.0f / 2048.0f) + bi;
                    const float ybn = (y - mu) * rs * ga + be;
                    const float h = vm + (ybn - vm) * 0.5f;
                    const bool sp = (h >= 1.0f);
                    vm = sp ? 0.f : h;
                    outp[((size_t)t * BN_T + bn) * C_ + c] = sp ? 1.0f : 0.0f;
                }
            }
        }
    }
}

// ---------------------------------------------------------------------------
// MFMA attention + LIF(0.5), whole-KV-in-LDS (verified round 8, unchanged).
// ---------------------------------------------------------------------------
__global__ __launch_bounds__(512, 2) void k_attn_mfma(
    const u16* __restrict__ qg, const u16* __restrict__ kg,
    const u16* __restrict__ vg, u16* __restrict__ s2t)
{
    __shared__ u16 kf[8][4096];    // full K  [jt][SW(kv,d)]   64KB
    __shared__ u16 vf[8][4096];    // full V^T [jt][SW(d,kv)]  64KB
    __shared__ u16 ssb[8][1024];   // per-wave S strip (16x64) 16KB

    const int id  = blockIdx.x;                 // 0..511
    const int lid = (id & 7) * 64 + (id >> 3);  // XCD swizzle; qt-siblings same XCD
    const int bh  = lid >> 2;                   // 0..127
    const int qt  = lid & 3;                    // 128-row q tile
    const int b   = bh >> 3, hh = bh & 7;

    const int tid  = threadIdx.x;
    const int w    = tid >> 6, lane = tid & 63;
    const int l15  = lane & 15, g = lane >> 4;

    const int vkv = (tid & 15) * 4;
    const int vd  = ((tid >> 4) & 15) * 4;

    bf16x8 qa[2];
    f32x4 vmem[4], oacc[4];
    #pragma unroll
    for (int d0 = 0; d0 < 4; ++d0) { vmem[d0] = {0,0,0,0}; oacc[d0] = {0,0,0,0}; }

    #pragma unroll 1
    for (int t = 0; t < T_; ++t) {
        const size_t base = ((size_t)t * (B_ * H_) + bh) * (size_t)(N_ * D_);
        if (t > 0) __syncthreads();            // readers of t-1 done

        {
            const size_t qrow = base + (size_t)(qt * 128 + 16 * w + l15) * D_;
            qa[0] = *reinterpret_cast<const bf16x8*>(qg + qrow + 8 * g);
            qa[1] = *reinterpret_cast<const bf16x8*>(qg + qrow + 32 + 8 * g);
        }
        {
            const u16* kb = kg + base;
            #pragma unroll
            for (int i = 0; i < 8; ++i) {
                const int r64 = tid >> 3;
                const int col = (tid & 7) * 8;
                const u16x8 v = *reinterpret_cast<const u16x8*>(kb + ((size_t)(tid + 512 * i)) * 8);
                *reinterpret_cast<u16x8*>(&kf[i][SW(r64, col)]) = v;
            }
        }
        {
            const u16* vb = vg + base;
            #pragma unroll
            for (int i = 0; i < 4; ++i) {
                const int jt = 2 * i + (tid >> 8);
                const int m0 = jt * 64;
                ushort4 r0 = *reinterpret_cast<const ushort4*>(vb + (size_t)(m0 + vkv + 0) * D_ + vd);
                ushort4 r1 = *reinterpret_cast<const ushort4*>(vb + (size_t)(m0 + vkv + 1) * D_ + vd);
                ushort4 r2 = *reinterpret_cast<const ushort4*>(vb + (size_t)(m0 + vkv + 2) * D_ + vd);
                ushort4 r3 = *reinterpret_cast<const ushort4*>(vb + (size_t)(m0 + vkv + 3) * D_ + vd);
                ushort4 wv4;
                wv4.x = r0.x; wv4.y = r1.x; wv4.z = r2.x; wv4.w = r3.x;
                *reinterpret_cast<ushort4*>(&vf[jt][SW(vd + 0, vkv)]) = wv4;
                wv4.x = r0.y; wv4.y = r1.y; wv4.z = r2.y; wv4.w = r3.y;
                *reinterpret_cast<ushort4*>(&vf[jt][SW(vd + 1, vkv)]) = wv4;
                wv4.x = r0.z; wv4.y = r1.z; wv4.z = r2.z; wv4.w = r3.z;
                *reinterpret_cast<ushort4*>(&vf[jt][SW(vd + 2, vkv)]) = wv4;
                wv4.x = r0.w; wv4.y = r1.w; wv4.z = r2.w; wv4.w = r3.w;
                *reinterpret_cast<ushort4*>(&vf[jt][SW(vd + 3, vkv)]) = wv4;
            }
        }
        __syncthreads();

        u16* sb = &ssb[w][0];
        #pragma unroll
        for (int jt = 0; jt < 8; ++jt) {
            __builtin_amdgcn_s_setprio(1);
            #pragma unroll
            for (int kvt = 0; kvt < 2; ++kvt) {
                f32x4 acc = {0.f, 0.f, 0.f, 0.f};
                #pragma unroll
                for (int c = 0; c < 2; ++c) {
                    const bf16x8 kb = *reinterpret_cast<const bf16x8*>(
                        &kf[jt][SW(16 * kvt + l15, 32 * c + 8 * g)]);
                    acc = __builtin_amdgcn_mfma_f32_16x16x32_bf16(qa[c], kb, acc, 0, 0, 0);
                }
                #pragma unroll
                for (int r = 0; r < 4; ++r)
                    sb[SW(4 * g + r, 16 * kvt + l15)] = f2bf_exact(acc[r]);
            }
            {
                const bf16x8 sa = *reinterpret_cast<const bf16x8*>(&sb[SW(l15, 8 * g)]);
                #pragma unroll
                for (int d0 = 0; d0 < 4; ++d0) {
                    const bf16x8 vb2 = *reinterpret_cast<const bf16x8*>(
                        &vf[jt][SW(16 * d0 + l15, 8 * g)]);
                    oacc[d0] = __builtin_amdgcn_mfma_f32_16x16x32_bf16(sa, vb2, oacc[d0], 0, 0, 0);
                }
            }
            #pragma unroll
            for (int kvt = 2; kvt < 4; ++kvt) {
                f32x4 acc = {0.f, 0.f, 0.f, 0.f};
                #pragma unroll
                for (int c = 0; c < 2; ++c) {
                    const bf16x8 kb = *reinterpret_cast<const bf16x8*>(
                        &kf[jt][SW(16 * kvt + l15, 32 * c + 8 * g)]);
                    acc = __builtin_amdgcn_mfma_f32_16x16x32_bf16(qa[c], kb, acc, 0, 0, 0);
                }
                #pragma unroll
                for (int r = 0; r < 4; ++r)
                    sb[SW(4 * g + r, 16 * kvt + l15)] = f2bf_exact(acc[r]);
            }
            {
                const bf16x8 sa = *reinterpret_cast<const bf16x8*>(&sb[SW(l15, 32 + 8 * g)]);
                #pragma unroll
                for (int d0 = 0; d0 < 4; ++d0) {
                    const bf16x8 vb2 = *reinterpret_cast<const bf16x8*>(
                        &vf[jt][SW(16 * d0 + l15, 32 + 8 * g)]);
                    oacc[d0] = __builtin_amdgcn_mfma_f32_16x16x32_bf16(sa, vb2, oacc[d0], 0, 0, 0);
                }
            }
            __builtin_amdgcn_s_setprio(0);
        }

        #pragma unroll
        for (int d0 = 0; d0 < 4; ++d0) {
            const int c = hh * 64 + d0 * 16 + l15;
            const int kb2 = c >> 5, kq = (c >> 3) & 3, e = c & 7;
            #pragma unroll
            for (int r = 0; r < 4; ++r) {
                const float o = oacc[d0][r] * 0.125f;
                const float h = vmem[d0][r] + (o - vmem[d0][r]) * 0.5f;
                const bool sp = (h >= 0.5f);
                vmem[d0][r] = sp ? 0.f : h;
                const int n = qt * 128 + 16 * w + 4 * g + r;
                const int bn = b * 512 + n;
                const int mt2 = bn >> 5;
                const int rr2 = (bn & 31) * 4 + t;
                const size_t off = (((size_t)mt2 * 16 + kb2) << 13) + (rr2 << 6)
                                 + (((kq ^ ((rr2 >> 1) & 3)) & 3) << 4) + (e << 1);
                *(u16*)((char*)s2t + off) = sp ? 0x3C00 : 0;   // fp16 1.0
            }
            oacc[d0] = {0.f, 0.f, 0.f, 0.f};
        }
    }
}

extern "C" void kernel_launch(void* const* d_in, const int* in_sizes, int n_in,
                              void* d_out, int out_size, void* d_ws, size_t ws_size,
                              hipStream_t stream)
{
    const float* x = (const float*)d_in[0];
    const float* W[4]  = {(const float*)d_in[1],  (const float*)d_in[7],  (const float*)d_in[13], (const float*)d_in[19]};
    const float* Bi[4] = {(const float*)d_in[2],  (const float*)d_in[8],  (const float*)d_in[14], (const float*)d_in[20]};
    const float* Ga[4] = {(const float*)d_in[3],  (const float*)d_in[9],  (const float*)d_in[15], (const float*)d_in[21]};
    const float* Be[4] = {(const float*)d_in[4],  (const float*)d_in[10], (const float*)d_in[16], (const float*)d_in[22]};
    const float* Mu[4] = {(const float*)d_in[5],  (const float*)d_in[11], (const float*)d_in[17], (const float*)d_in[23]};
    const float* Va[4] = {(const float*)d_in[6],  (const float*)d_in[12], (const float*)d_in[18], (const float*)d_in[24]};

    const size_t SPK = (size_t)T_ * B_ * N_ * C_;   // 16,777,216
    const size_t WSZ = (size_t)C_ * C_;             // 262,144
    u16* qb  = (u16*)d_ws;          // bf16 spikes [T,B,H,N,D]
    u16* kbf = qb + SPK;
    u16* vbf = kbf + SPK;
    u16* x1t = vbf + SPK;           // tiled x1; reused as s2t after linears
    u16* x2t = x1t + SPK;           // tiled x2
    u16* wt  = x2t + SPK;           // 4 weights x 2 splits x WSZ
    u16* s2t = x1t;                 // attn output overlays x1t (dead by then)

    dim3 blk(256);
    k_split_x<<<4096, blk, 0, stream>>>(x, x1t, x2t);
    for (int i = 0; i < 4; ++i)
        k_split_w<<<64, blk, 0, stream>>>(W[i], wt + (2*i) * WSZ, wt + (2*i+1) * WSZ);

    k_linear_qkv<<<3072, blk, 0, stream>>>(x1t, x2t, wt,
        Bi[0], Ga[0], Be[0], Mu[0], Va[0],
        Bi[1], Ga[1], Be[1], Mu[1], Va[1],
        Bi[2], Ga[2], Be[2], Mu[2], Va[2],
        qb, kbf, vbf);
    k_attn_mfma<<<512, dim3(512), 0, stream>>>(qb, kbf, vbf, s2t);
    k_linear_out<<<1024, blk, 0, stream>>>(s2t, wt + 6*WSZ, wt + 7*WSZ,
        Bi[3], Ga[3], Be[3], Mu[3], Va[3], (float*)d_out);
}

// Round 14
// 297.602 us; speedup vs baseline: 1.0640x; 1.0640x over previous
//
#include <hip/hip_runtime.h>
#include <hip/hip_bf16.h>
#include <hip/hip_fp16.h>
#include <cstddef>
#include <cstdint>

#define T_ 4
#define B_ 16
#define N_ 512
#define C_ 512
#define H_ 8
#define D_ 64
#define BN_T (B_*N_)   // 8192

typedef unsigned short u16;
typedef __attribute__((ext_vector_type(8))) short bf16x8;       // 8 bf16
typedef __attribute__((ext_vector_type(8))) _Float16 f16x8;     // 8 fp16
typedef __attribute__((ext_vector_type(8))) unsigned short u16x8;
typedef __attribute__((ext_vector_type(4))) float f32x4;

__device__ __forceinline__ u16 f2bf_exact(float f) {
    union { float f; unsigned u; } x; x.f = f; return (u16)(x.u >> 16);
}
// 2-term exact fp16 split: f == h1 + h2/2048 + tail(<=2^-22|f|)
__device__ __forceinline__ void split2(float f, u16& h1, u16& h2) {
    const __half a = __float2half(f);                   // RNE
    const float r = (f - __half2float(a)) * 2048.0f;    // exact (Sterbenz + pow2)
    const __half b = __float2half(r);
    h1 = __half_as_ushort(a); h2 = __half_as_ushort(b);
}
// XOR swizzle, 16B granularity, BYTE offset into a [128][32] fp16 tile (64B rows)
__device__ __forceinline__ int swz(int rr, int q) {
    return (rr << 6) + (((q ^ ((rr >> 1) & 3)) & 3) << 4);
}
// attention LDS swizzle (element index into [64][64] u16 tiles)
__device__ __forceinline__ int SW(int row, int col) {
    return (row << 6) + (col ^ ((row & 7) << 3));
}
// async global->LDS, 16B per lane (dest = uniform base + lane*16)
__device__ __forceinline__ void gload16(const void* g, void* l) {
    __builtin_amdgcn_global_load_lds(
        (const __attribute__((address_space(1))) unsigned int*)g,
        (__attribute__((address_space(3))) unsigned int*)l, 16, 0, 0);
}

// phase macro for k_linear_out (verified round 10/12 structure)
#define PHASE2T(p, STAGE, WAIT) do {                                          \
    const int cc_ = 64 * wc + 16 * (p);                                       \
    const int rrB_ = (cc_ & 127) + l15;                                       \
    const char* LB_ = L + (1 + (cc_ >> 7)) * 8192;                            \
    const f16x8 b1_ = *reinterpret_cast<const f16x8*>(LB_ + swz(rrB_, g));    \
    const f16x8 b2_ = *reinterpret_cast<const f16x8*>(LB_ + 16384 + swz(rrB_, g)); \
    STAGE;                                                                    \
    WAIT;                                                                     \
    __builtin_amdgcn_sched_barrier(0);                                        \
    __builtin_amdgcn_s_barrier();                                             \
    asm volatile("s_waitcnt lgkmcnt(0)" ::: "memory");                        \
    __builtin_amdgcn_sched_barrier(0);                                        \
    __builtin_amdgcn_s_setprio(1);                                            \
    _Pragma("unroll")                                                         \
    for (int rt_ = 0; rt_ < 4; ++rt_) {                                       \
        accA[rt_][p] = __builtin_amdgcn_mfma_f32_16x16x32_f16(a1[rt_], b1_, accA[rt_][p], 0, 0, 0); \
        accB[rt_][p] = __builtin_amdgcn_mfma_f32_16x16x32_f16(a1[rt_], b2_, accB[rt_][p], 0, 0, 0); \
    }                                                                         \
    __builtin_amdgcn_s_setprio(0);                                            \
    __builtin_amdgcn_s_barrier();                                             \
} while (0)

// ---------------------------------------------------------------------------
// FUSED split kernel: blocks [0,4096) split x (fp32 [T,BN,C] -> tile-major
// pre-swizzled fp16 x1t/x2t); blocks [4096,4352) split the 4 weight matrices.
// Per-element arithmetic identical to the verified separate kernels.
// ---------------------------------------------------------------------------
__global__ __launch_bounds__(256) void k_split_all(
    const float* __restrict__ x,
    const float* __restrict__ w0, const float* __restrict__ w1,
    const float* __restrict__ w2, const float* __restrict__ w3,
    u16* __restrict__ x1t, u16* __restrict__ x2t, u16* __restrict__ wt)
{
    const int tid = threadIdx.x;
    const int rr = tid >> 1, kh = tid & 1;
    const size_t WSZ = (size_t)C_ * C_;

    const float* src;
    char *d1, *d2;
    if (blockIdx.x < 4096) {
        const int tile = blockIdx.x;           // mt*16 + kb
        const int mt = tile >> 4, kb = tile & 15;
        const int t = rr & 3, bn = mt * 32 + (rr >> 2);
        src = x + ((size_t)t * BN_T + bn) * C_ + kb * 32 + kh * 16;
        d1 = (char*)(x1t + ((size_t)tile << 12));
        d2 = (char*)(x2t + ((size_t)tile << 12));
    } else {
        const int r = blockIdx.x - 4096;       // 0..255
        const int wi = r >> 6;                 // which weight 0..3
        const int tile = r & 63;               // nt*16 + kb
        const int nt = tile >> 4, kb = tile & 15;
        const int c = nt * 128 + rr;
        const float* w = wi == 0 ? w0 : wi == 1 ? w1 : wi == 2 ? w2 : w3;
        src = w + (size_t)c * C_ + kb * 32 + kh * 16;
        d1 = (char*)(wt + (size_t)(2 * wi) * WSZ + ((size_t)tile << 12));
        d2 = (char*)(wt + (size_t)(2 * wi + 1) * WSZ + ((size_t)tile << 12));
    }

    float f[16];
    *reinterpret_cast<float4*>(f + 0)  = *reinterpret_cast<const float4*>(src + 0);
    *reinterpret_cast<float4*>(f + 4)  = *reinterpret_cast<const float4*>(src + 4);
    *reinterpret_cast<float4*>(f + 8)  = *reinterpret_cast<const float4*>(src + 8);
    *reinterpret_cast<float4*>(f + 12) = *reinterpret_cast<const float4*>(src + 12);
    #pragma unroll
    for (int j = 0; j < 2; ++j) {
        u16x8 p1, p2;
        #pragma unroll
        for (int e = 0; e < 8; ++e) { u16 h1, h2; split2(f[8*j+e], h1, h2); p1[e] = h1; p2[e] = h2; }
        const int q = 2 * kh + j;
        *reinterpret_cast<u16x8*>(d1 + swz(rr, q)) = p1;
        *reinterpret_cast<u16x8*>(d2 + swz(rr, q)) = p2;
    }
}

// ---------------------------------------------------------------------------
// Merged Q/K/V split-fp16 MFMA Linear -> BN -> LIF(v_th=1) over T=4.
// Round-12 verified kernel (2-buffer, __syncthreads, stage-before-compute,
// 2x2 wave grid, 128x128 tile, 16x16x32 MFMAs). 153.5 us, 0 bank conflicts.
// ---------------------------------------------------------------------------
__global__ __launch_bounds__(256, 2) void k_linear_qkv(
    const u16* __restrict__ a1t, const u16* __restrict__ a2t,
    const u16* __restrict__ wt_base,
    const float* __restrict__ bi0, const float* __restrict__ ga0, const float* __restrict__ be0,
    const float* __restrict__ mu0, const float* __restrict__ va0,
    const float* __restrict__ bi1, const float* __restrict__ ga1, const float* __restrict__ be1,
    const float* __restrict__ mu1, const float* __restrict__ va1,
    const float* __restrict__ bi2, const float* __restrict__ ga2, const float* __restrict__ be2,
    const float* __restrict__ mu2, const float* __restrict__ va2,
    u16* __restrict__ oq, u16* __restrict__ ok, u16* __restrict__ ov)
{
    __shared__ u16 lds[2][4][4096];   // [buf][A1,A2,B1,B2][8KB tile] = 64KB

    const int dd  = blockIdx.x;                    // 0..3071
    const int lid = (dd & 7) * 384 + (dd >> 3);    // XCD swizzle (bijective)
    const int mt  = lid / 12;                      // 0..255
    const int ntg = lid - mt * 12;                 // 0..11
    const int li  = ntg >> 2;                      // which linear 0..2
    const int nt  = ntg & 3;
    const int bn0 = mt * 32;
    const int c0  = nt * 128;

    const float* bias  = li == 0 ? bi0 : li == 1 ? bi1 : bi2;
    const float* gamma = li == 0 ? ga0 : li == 1 ? ga1 : ga2;
    const float* beta  = li == 0 ? be0 : li == 1 ? be1 : be2;
    const float* mean  = li == 0 ? mu0 : li == 1 ? mu1 : mu2;
    const float* var   = li == 0 ? va0 : li == 1 ? va1 : va2;
    u16* outp = li == 0 ? oq : li == 1 ? ok : ov;

    const size_t WSZ = (size_t)C_ * C_;
    const u16* w1t = wt_base + (size_t)(2 * li) * WSZ;
    const u16* w2t = wt_base + (size_t)(2 * li + 1) * WSZ;

    const int tid = threadIdx.x;
    const int wv  = tid >> 6, lane = tid & 63;
    const int l15 = lane & 15, g = (lane >> 4) & 3;
    const int wr  = wv >> 1, wc = wv & 1;          // 2x2 wave grid, wave 64x64
    const int go  = wv * 2048 + lane * 16;
    const int lo  = wv * 2048;

    f32x4 accA[4][4], accB[4][4];
    #pragma unroll
    for (int rt = 0; rt < 4; ++rt)
        #pragma unroll
        for (int ct = 0; ct < 4; ++ct) { accA[rt][ct] = {0,0,0,0}; accB[rt][ct] = {0,0,0,0}; }

    const size_t abase = (size_t)mt * 16, bbase = (size_t)nt * 16;

    auto stage = [&](int buf, int kb) {            // 8 gload16 / thread
        char* L = (char*)&lds[buf][0][0];
        const char* ga1p = (const char*)(a1t + ((abase + kb) << 12)) + go;
        const char* ga2p = (const char*)(a2t + ((abase + kb) << 12)) + go;
        const char* gb1 = (const char*)(w1t + ((bbase + kb) << 12)) + go;
        const char* gb2 = (const char*)(w2t + ((bbase + kb) << 12)) + go;
        gload16(ga1p,        L + lo);
        gload16(ga1p + 1024, L + lo + 1024);
        gload16(ga2p,        L + 8192 + lo);
        gload16(ga2p + 1024, L + 8192 + lo + 1024);
        gload16(gb1,        L + 16384 + lo);
        gload16(gb1 + 1024, L + 16384 + lo + 1024);
        gload16(gb2,        L + 24576 + lo);
        gload16(gb2 + 1024, L + 24576 + lo + 1024);
    };

    stage(0, 0);
    __syncthreads();

    #pragma unroll 1
    for (int kb = 0; kb < 16; ++kb) {
        const int buf = kb & 1;
        if (kb < 15) stage(buf ^ 1, kb + 1);       // async, flies under MFMAs
        const char* L = (const char*)&lds[buf][0][0];
        f16x8 a1[4], a2[4];
        #pragma unroll
        for (int rt = 0; rt < 4; ++rt) {
            const int rr = 64 * wr + 16 * rt + l15;
            a1[rt] = *reinterpret_cast<const f16x8*>(L + swz(rr, g));
            a2[rt] = *reinterpret_cast<const f16x8*>(L + 8192 + swz(rr, g));
        }
        #pragma unroll
        for (int ct = 0; ct < 4; ++ct) {
            const int rr2 = 64 * wc + 16 * ct + l15;
            const f16x8 b1 = *reinterpret_cast<const f16x8*>(L + 16384 + swz(rr2, g));
            const f16x8 b2 = *reinterpret_cast<const f16x8*>(L + 24576 + swz(rr2, g));
            #pragma unroll
            for (int rt = 0; rt < 4; ++rt) {
                accA[rt][ct] = __builtin_amdgcn_mfma_f32_16x16x32_f16(a1[rt], b1, accA[rt][ct], 0, 0, 0);
                accB[rt][ct] = __builtin_amdgcn_mfma_f32_16x16x32_f16(a2[rt], b1, accB[rt][ct], 0, 0, 0);
                accB[rt][ct] = __builtin_amdgcn_mfma_f32_16x16x32_f16(a1[rt], b2, accB[rt][ct], 0, 0, 0);
            }
        }
        __syncthreads();   // drains stage loads + everyone's reads
    }

    // epilogue: reconstruct -> bias -> BN -> LIF(v_th=1) over reg r==t
    #pragma unroll
    for (int ct = 0; ct < 4; ++ct) {
        const int c = c0 + 64 * wc + 16 * ct + l15;
        const float rs = 1.0f / sqrtf(var[c] + 1e-5f);
        const float ga = gamma[c], be = beta[c], mu = mean[c], bi = bias[c];
        #pragma unroll
        for (int rt = 0; rt < 4; ++rt) {
            const int bn = bn0 + 16 * wr + 4 * rt + g;
            float vm = 0.f;
            #pragma unroll
            for (int r = 0; r < 4; ++r) {
                const float y = accA[rt][ct][r] + accB[rt][ct][r] * (1.0f / 2048.0f) + bi;
                const float ybn = (y - mu) * rs * ga + be;
                const float h = vm + (ybn - vm) * 0.5f;
                const bool sp = (h >= 1.0f);
                vm = sp ? 0.f : h;
                const int b = bn >> 9, n = bn & 511;
                const int hh = c >> 6, d2 = c & 63;
                outp[((((size_t)r * B_ + b) * H_ + hh) * N_ + n) * D_ + d2] = sp ? 0x3F80 : 0;
            }
        }
    }
}

// ---------------------------------------------------------------------------
// Final split-fp16 MFMA Linear (spike fp16 input, 2 terms) -> BN -> LIF,
// fp32 0/1 out. Verified round-10/12 phase structure (unchanged).
// ---------------------------------------------------------------------------
__global__ __launch_bounds__(512, 2) void k_linear_out(
    const u16* __restrict__ a1t,
    const u16* __restrict__ w1t, const u16* __restrict__ w2t,
    const float* __restrict__ bias, const float* __restrict__ gamma,
    const float* __restrict__ beta, const float* __restrict__ mean,
    const float* __restrict__ var, float* __restrict__ outp)
{
    __shared__ u16 lds[3][5][4096];   // 3 x 40KB = 120KB

    const int dd  = blockIdx.x;                   // 0..511
    const int lid = (dd & 7) * 64 + (dd >> 3);
    const int mt  = lid >> 1;                     // 0..255
    const int nt  = lid & 1;
    const int bn0 = mt * 32;
    const int c0  = nt * 256;

    const int tid = threadIdx.x;
    const int wv  = tid >> 6, lane = tid & 63;
    const int l15 = lane & 15, g = (lane >> 4) & 3;
    const int wr  = wv >> 2, wc = wv & 3;
    const int so  = tid * 16;

    f32x4 accA[4][4], accB[4][4];
    #pragma unroll
    for (int rt = 0; rt < 4; ++rt)
        #pragma unroll
        for (int ct = 0; ct < 4; ++ct) { accA[rt][ct] = {0,0,0,0}; accB[rt][ct] = {0,0,0,0}; }

    const size_t abase  = (size_t)mt * 16;
    const size_t bbase0 = (size_t)(nt * 2 + 0) * 16;
    const size_t bbase1 = (size_t)(nt * 2 + 1) * 16;
    char* const L0 = (char*)&lds[0][0][0];

    auto s0 = [&](int kb) { char* Ls = L0 + (kb % 3) * 40960;
        gload16((const char*)(a1t + ((abase  + kb) << 12)) + so, Ls + 0 * 8192 + so);
        gload16((const char*)(w1t + ((bbase0 + kb) << 12)) + so, Ls + 1 * 8192 + so); };
    auto s1 = [&](int kb) { char* Ls = L0 + (kb % 3) * 40960;
        gload16((const char*)(w1t + ((bbase1 + kb) << 12)) + so, Ls + 2 * 8192 + so);
        gload16((const char*)(w2t + ((bbase0 + kb) << 12)) + so, Ls + 3 * 8192 + so); };
    auto s2 = [&](int kb) { char* Ls = L0 + (kb % 3) * 40960;
        gload16((const char*)(w2t + ((bbase1 + kb) << 12)) + so, Ls + 4 * 8192 + so); };

    s0(0); s1(0); s2(0);
    s0(1); s1(1); s2(1);
    __builtin_amdgcn_sched_barrier(0);
    asm volatile("s_waitcnt vmcnt(5)" ::: "memory");
    __builtin_amdgcn_s_barrier();
    __builtin_amdgcn_sched_barrier(0);

    #pragma unroll 1
    for (int k = 0; k < 16; ++k) {
        const char* L = L0 + (k % 3) * 40960;
        f16x8 a1[4];
        #pragma unroll
        for (int rt = 0; rt < 4; ++rt) {
            const int rr = 64 * wr + 16 * rt + l15;
            a1[rt] = *reinterpret_cast<const f16x8*>(L + swz(rr, g));
        }
        const bool st = (k <= 13);
        PHASE2T(0, if (st) s0(k + 2), );
        PHASE2T(1, if (st) s1(k + 2), );
        PHASE2T(2, if (st) s2(k + 2), );
        if (k < 14) { PHASE2T(3, , asm volatile("s_waitcnt vmcnt(5)" ::: "memory")); }
        else        { PHASE2T(3, , asm volatile("s_waitcnt vmcnt(0)" ::: "memory")); }
    }

    #pragma unroll
    for (int ct = 0; ct < 4; ++ct) {
        const int c = c0 + 64 * wc + 16 * ct + l15;
        const float rs = 1.0f / sqrtf(var[c] + 1e-5f);
        const float ga = gamma[c], be = beta[c], mu = mean[c], bi = bias[c];
        #pragma unroll
        for (int rt = 0; rt < 4; ++rt) {
            const int bn = bn0 + 16 * wr + 4 * rt + g;
            float vm = 0.f;
            #pragma unroll
            for (int r = 0; r < 4; ++r) {
                const float y = accA[rt][ct][r] + accB[rt][ct][r] * (1.0f / 2048.0f) + bi;
                const float ybn = (y - mu) * rs * ga + be;
                const float h = vm + (ybn - vm) * 0.5f;
                const bool sp = (h >= 1.0f);
                vm = sp ? 0.f : h;
                outp[((size_t)r * BN_T + bn) * C_ + c] = sp ? 1.0f : 0.0f;
            }
        }
    }
}

// ---------------------------------------------------------------------------
// MFMA attention + LIF(0.5), whole-KV-in-LDS (verified round 8, unchanged).
// ---------------------------------------------------------------------------
__global__ __launch_bounds__(512, 2) void k_attn_mfma(
    const u16* __restrict__ qg, const u16* __restrict__ kg,
    const u16* __restrict__ vg, u16* __restrict__ s2t)
{
    __shared__ u16 kf[8][4096];    // full K  [jt][SW(kv,d)]   64KB
    __shared__ u16 vf[8][4096];    // full V^T [jt][SW(d,kv)]  64KB
    __shared__ u16 ssb[8][1024];   // per-wave S strip (16x64) 16KB

    const int id  = blockIdx.x;                 // 0..511
    const int lid = (id & 7) * 64 + (id >> 3);  // XCD swizzle; qt-siblings same XCD
    const int bh  = lid >> 2;                   // 0..127
    const int qt  = lid & 3;                    // 128-row q tile
    const int b   = bh >> 3, hh = bh & 7;

    const int tid  = threadIdx.x;
    const int w    = tid >> 6, lane = tid & 63;
    const int l15  = lane & 15, g = lane >> 4;

    const int vkv = (tid & 15) * 4;
    const int vd  = ((tid >> 4) & 15) * 4;

    bf16x8 qa[2];
    f32x4 vmem[4], oacc[4];
    #pragma unroll
    for (int d0 = 0; d0 < 4; ++d0) { vmem[d0] = {0,0,0,0}; oacc[d0] = {0,0,0,0}; }

    #pragma unroll 1
    for (int t = 0; t < T_; ++t) {
        const size_t base = ((size_t)t * (B_ * H_) + bh) * (size_t)(N_ * D_);
        if (t > 0) __syncthreads();            // readers of t-1 done

        {
            const size_t qrow = base + (size_t)(qt * 128 + 16 * w + l15) * D_;
            qa[0] = *reinterpret_cast<const bf16x8*>(qg + qrow + 8 * g);
            qa[1] = *reinterpret_cast<const bf16x8*>(qg + qrow + 32 + 8 * g);
        }
        {
            const u16* kb = kg + base;
            #pragma unroll
            for (int i = 0; i < 8; ++i) {
                const int r64 = tid >> 3;
                const int col = (tid & 7) * 8;
                const u16x8 v = *reinterpret_cast<const u16x8*>(kb + ((size_t)(tid + 512 * i)) * 8);
                *reinterpret_cast<u16x8*>(&kf[i][SW(r64, col)]) = v;
            }
        }
        {
            const u16* vb = vg + base;
            #pragma unroll
            for (int i = 0; i < 4; ++i) {
                const int jt = 2 * i + (tid >> 8);
                const int m0 = jt * 64;
                ushort4 r0 = *reinterpret_cast<const ushort4*>(vb + (size_t)(m0 + vkv + 0) * D_ + vd);
                ushort4 r1 = *reinterpret_cast<const ushort4*>(vb + (size_t)(m0 + vkv + 1) * D_ + vd);
                ushort4 r2 = *reinterpret_cast<const ushort4*>(vb + (size_t)(m0 + vkv + 2) * D_ + vd);
                ushort4 r3 = *reinterpret_cast<const ushort4*>(vb + (size_t)(m0 + vkv + 3) * D_ + vd);
                ushort4 wv4;
                wv4.x = r0.x; wv4.y = r1.x; wv4.z = r2.x; wv4.w = r3.x;
                *reinterpret_cast<ushort4*>(&vf[jt][SW(vd + 0, vkv)]) = wv4;
                wv4.x = r0.y; wv4.y = r1.y; wv4.z = r2.y; wv4.w = r3.y;
                *reinterpret_cast<ushort4*>(&vf[jt][SW(vd + 1, vkv)]) = wv4;
                wv4.x = r0.z; wv4.y = r1.z; wv4.z = r2.z; wv4.w = r3.z;
                *reinterpret_cast<ushort4*>(&vf[jt][SW(vd + 2, vkv)]) = wv4;
                wv4.x = r0.w; wv4.y = r1.w; wv4.z = r2.w; wv4.w = r3.w;
                *reinterpret_cast<ushort4*>(&vf[jt][SW(vd + 3, vkv)]) = wv4;
            }
        }
        __syncthreads();

        u16* sb = &ssb[w][0];
        #pragma unroll
        for (int jt = 0; jt < 8; ++jt) {
            __builtin_amdgcn_s_setprio(1);
            #pragma unroll
            for (int kvt = 0; kvt < 2; ++kvt) {
                f32x4 acc = {0.f, 0.f, 0.f, 0.f};
                #pragma unroll
                for (int c = 0; c < 2; ++c) {
                    const bf16x8 kb = *reinterpret_cast<const bf16x8*>(
                        &kf[jt][SW(16 * kvt + l15, 32 * c + 8 * g)]);
                    acc = __builtin_amdgcn_mfma_f32_16x16x32_bf16(qa[c], kb, acc, 0, 0, 0);
                }
                #pragma unroll
                for (int r = 0; r < 4; ++r)
                    sb[SW(4 * g + r, 16 * kvt + l15)] = f2bf_exact(acc[r]);
            }
            {
                const bf16x8 sa = *reinterpret_cast<const bf16x8*>(&sb[SW(l15, 8 * g)]);
                #pragma unroll
                for (int d0 = 0; d0 < 4; ++d0) {
                    const bf16x8 vb2 = *reinterpret_cast<const bf16x8*>(
                        &vf[jt][SW(16 * d0 + l15, 8 * g)]);
                    oacc[d0] = __builtin_amdgcn_mfma_f32_16x16x32_bf16(sa, vb2, oacc[d0], 0, 0, 0);
                }
            }
            #pragma unroll
            for (int kvt = 2; kvt < 4; ++kvt) {
                f32x4 acc = {0.f, 0.f, 0.f, 0.f};
                #pragma unroll
                for (int c = 0; c < 2; ++c) {
                    const bf16x8 kb = *reinterpret_cast<const bf16x8*>(
                        &kf[jt][SW(16 * kvt + l15, 32 * c + 8 * g)]);
                    acc = __builtin_amdgcn_mfma_f32_16x16x32_bf16(qa[c], kb, acc, 0, 0, 0);
                }
                #pragma unroll
                for (int r = 0; r < 4; ++r)
                    sb[SW(4 * g + r, 16 * kvt + l15)] = f2bf_exact(acc[r]);
            }
            {
                const bf16x8 sa = *reinterpret_cast<const bf16x8*>(&sb[SW(l15, 32 + 8 * g)]);
                #pragma unroll
                for (int d0 = 0; d0 < 4; ++d0) {
                    const bf16x8 vb2 = *reinterpret_cast<const bf16x8*>(
                        &vf[jt][SW(16 * d0 + l15, 32 + 8 * g)]);
                    oacc[d0] = __builtin_amdgcn_mfma_f32_16x16x32_bf16(sa, vb2, oacc[d0], 0, 0, 0);
                }
            }
            __builtin_amdgcn_s_setprio(0);
        }

        #pragma unroll
        for (int d0 = 0; d0 < 4; ++d0) {
            const int c = hh * 64 + d0 * 16 + l15;
            const int kb2 = c >> 5, kq = (c >> 3) & 3, e = c & 7;
            #pragma unroll
            for (int r = 0; r < 4; ++r) {
                const float o = oacc[d0][r] * 0.125f;
                const float h = vmem[d0][r] + (o - vmem[d0][r]) * 0.5f;
                const bool sp = (h >= 0.5f);
                vmem[d0][r] = sp ? 0.f : h;
                const int n = qt * 128 + 16 * w + 4 * g + r;
                const int bn = b * 512 + n;
                const int mt2 = bn >> 5;
                const int rr2 = (bn & 31) * 4 + t;
                const size_t off = (((size_t)mt2 * 16 + kb2) << 13) + (rr2 << 6)
                                 + (((kq ^ ((rr2 >> 1) & 3)) & 3) << 4) + (e << 1);
                *(u16*)((char*)s2t + off) = sp ? 0x3C00 : 0;   // fp16 1.0
            }
            oacc[d0] = {0.f, 0.f, 0.f, 0.f};
        }
    }
}

extern "C" void kernel_launch(void* const* d_in, const int* in_sizes, int n_in,
                              void* d_out, int out_size, void* d_ws, size_t ws_size,
                              hipStream_t stream)
{
    const float* x = (const float*)d_in[0];
    const float* W[4]  = {(const float*)d_in[1],  (const float*)d_in[7],  (const float*)d_in[13], (const float*)d_in[19]};
    const float* Bi[4] = {(const float*)d_in[2],  (const float*)d_in[8],  (const float*)d_in[14], (const float*)d_in[20]};
    const float* Ga[4] = {(const float*)d_in[3],  (const float*)d_in[9],  (const float*)d_in[15], (const float*)d_in[21]};
    const float* Be[4] = {(const float*)d_in[4],  (const float*)d_in[10], (const float*)d_in[16], (const float*)d_in[22]};
    const float* Mu[4] = {(const float*)d_in[5],  (const float*)d_in[11], (const float*)d_in[17], (const float*)d_in[23]};
    const float* Va[4] = {(const float*)d_in[6],  (const float*)d_in[12], (const float*)d_in[18], (const float*)d_in[24]};

    const size_t SPK = (size_t)T_ * B_ * N_ * C_;   // 16,777,216
    const size_t WSZ = (size_t)C_ * C_;             // 262,144
    u16* qb  = (u16*)d_ws;          // bf16 spikes [T,B,H,N,D]
    u16* kbf = qb + SPK;
    u16* vbf = kbf + SPK;
    u16* x1t = vbf + SPK;           // tiled x1; reused as s2t after linears
    u16* x2t = x1t + SPK;           // tiled x2
    u16* wt  = x2t + SPK;           // 4 weights x 2 splits x WSZ
    u16* s2t = x1t;                 // attn output overlays x1t (dead by then)

    dim3 blk(256);
    k_split_all<<<4352, blk, 0, stream>>>(x, W[0], W[1], W[2], W[3], x1t, x2t, wt);

    k_linear_qkv<<<3072, blk, 0, stream>>>(x1t, x2t, wt,
        Bi[0], Ga[0], Be[0], Mu[0], Va[0],
        Bi[1], Ga[1], Be[1], Mu[1], Va[1],
        Bi[2], Ga[2], Be[2], Mu[2], Va[2],
        qb, kbf, vbf);
    k_attn_mfma<<<512, dim3(512), 0, stream>>>(qb, kbf, vbf, s2t);
    k_linear_out<<<512, dim3(512), 0, stream>>>(s2t, wt + 6*WSZ, wt + 7*WSZ,
        Bi[3], Ga[3], Be[3], Mu[3], Va[3], (float*)d_out);
}

// Round 15
// 276.124 us; speedup vs baseline: 1.1468x; 1.0778x over previous
//
#include <hip/hip_runtime.h>
#include <hip/hip_bf16.h>
#include <hip/hip_fp16.h>
#include <cstddef>
#include <cstdint>

#define T_ 4
#define B_ 16
#define N_ 512
#define C_ 512
#define H_ 8
#define D_ 64
#define BN_T (B_*N_)   // 8192

typedef unsigned short u16;
typedef __attribute__((ext_vector_type(8))) short bf16x8;       // 8 bf16
typedef __attribute__((ext_vector_type(8))) _Float16 f16x8;     // 8 fp16
typedef __attribute__((ext_vector_type(8))) unsigned short u16x8;
typedef __attribute__((ext_vector_type(4))) float f32x4;

__device__ __forceinline__ u16 f2bf_exact(float f) {
    union { float f; unsigned u; } x; x.f = f; return (u16)(x.u >> 16);
}
// 2-term exact fp16 split: f == h1 + h2/2048 + tail(<=2^-22|f|)
__device__ __forceinline__ void split2(float f, u16& h1, u16& h2) {
    const __half a = __float2half(f);                   // RNE
    const float r = (f - __half2float(a)) * 2048.0f;    // exact (Sterbenz + pow2)
    const __half b = __float2half(r);
    h1 = __half_as_ushort(a); h2 = __half_as_ushort(b);
}
// XOR swizzle, 16B granularity, BYTE offset into a [128][32] fp16 tile (64B rows)
__device__ __forceinline__ int swz(int rr, int q) {
    return (rr << 6) + (((q ^ ((rr >> 1) & 3)) & 3) << 4);
}
// attention LDS swizzle (element index into [64][64] u16 tiles)
__device__ __forceinline__ int SW(int row, int col) {
    return (row << 6) + (col ^ ((row & 7) << 3));
}
// async global->LDS, 16B per lane (dest = uniform base + lane*16)
__device__ __forceinline__ void gload16(const void* g, void* l) {
    __builtin_amdgcn_global_load_lds(
        (const __attribute__((address_space(1))) unsigned int*)g,
        (__attribute__((address_space(3))) unsigned int*)l, 16, 0, 0);
}

// ---------------------------------------------------------------------------
// FUSED split kernel (verified round 14): blocks [0,4096) split x; blocks
// [4096,4352) split the 4 weight matrices. Tile-major pre-swizzled fp16 out.
// ---------------------------------------------------------------------------
__global__ __launch_bounds__(256) void k_split_all(
    const float* __restrict__ x,
    const float* __restrict__ w0, const float* __restrict__ w1,
    const float* __restrict__ w2, const float* __restrict__ w3,
    u16* __restrict__ x1t, u16* __restrict__ x2t, u16* __restrict__ wt)
{
    const int tid = threadIdx.x;
    const int rr = tid >> 1, kh = tid & 1;
    const size_t WSZ = (size_t)C_ * C_;

    const float* src;
    char *d1, *d2;
    if (blockIdx.x < 4096) {
        const int tile = blockIdx.x;           // mt*16 + kb
        const int mt = tile >> 4, kb = tile & 15;
        const int t = rr & 3, bn = mt * 32 + (rr >> 2);
        src = x + ((size_t)t * BN_T + bn) * C_ + kb * 32 + kh * 16;
        d1 = (char*)(x1t + ((size_t)tile << 12));
        d2 = (char*)(x2t + ((size_t)tile << 12));
    } else {
        const int r = blockIdx.x - 4096;       // 0..255
        const int wi = r >> 6;                 // which weight 0..3
        const int tile = r & 63;               // nt*16 + kb
        const int nt = tile >> 4, kb = tile & 15;
        const int c = nt * 128 + rr;
        const float* w = wi == 0 ? w0 : wi == 1 ? w1 : wi == 2 ? w2 : w3;
        src = w + (size_t)c * C_ + kb * 32 + kh * 16;
        d1 = (char*)(wt + (size_t)(2 * wi) * WSZ + ((size_t)tile << 12));
        d2 = (char*)(wt + (size_t)(2 * wi + 1) * WSZ + ((size_t)tile << 12));
    }

    float f[16];
    *reinterpret_cast<float4*>(f + 0)  = *reinterpret_cast<const float4*>(src + 0);
    *reinterpret_cast<float4*>(f + 4)  = *reinterpret_cast<const float4*>(src + 4);
    *reinterpret_cast<float4*>(f + 8)  = *reinterpret_cast<const float4*>(src + 8);
    *reinterpret_cast<float4*>(f + 12) = *reinterpret_cast<const float4*>(src + 12);
    #pragma unroll
    for (int j = 0; j < 2; ++j) {
        u16x8 p1, p2;
        #pragma unroll
        for (int e = 0; e < 8; ++e) { u16 h1, h2; split2(f[8*j+e], h1, h2); p1[e] = h1; p2[e] = h2; }
        const int q = 2 * kh + j;
        *reinterpret_cast<u16x8*>(d1 + swz(rr, q)) = p1;
        *reinterpret_cast<u16x8*>(d2 + swz(rr, q)) = p2;
    }
}

// ---------------------------------------------------------------------------
// Merged Q/K/V split-fp16 MFMA Linear -> BN -> LIF(v_th=1) over T=4.
// Round-12/14 verified kernel (best of 6 variants: 153.5us, 0 conflicts).
// ---------------------------------------------------------------------------
__global__ __launch_bounds__(256, 2) void k_linear_qkv(
    const u16* __restrict__ a1t, const u16* __restrict__ a2t,
    const u16* __restrict__ wt_base,
    const float* __restrict__ bi0, const float* __restrict__ ga0, const float* __restrict__ be0,
    const float* __restrict__ mu0, const float* __restrict__ va0,
    const float* __restrict__ bi1, const float* __restrict__ ga1, const float* __restrict__ be1,
    const float* __restrict__ mu1, const float* __restrict__ va1,
    const float* __restrict__ bi2, const float* __restrict__ ga2, const float* __restrict__ be2,
    const float* __restrict__ mu2, const float* __restrict__ va2,
    u16* __restrict__ oq, u16* __restrict__ ok, u16* __restrict__ ov)
{
    __shared__ u16 lds[2][4][4096];   // [buf][A1,A2,B1,B2][8KB tile] = 64KB

    const int dd  = blockIdx.x;                    // 0..3071
    const int lid = (dd & 7) * 384 + (dd >> 3);    // XCD swizzle (bijective)
    const int mt  = lid / 12;                      // 0..255
    const int ntg = lid - mt * 12;                 // 0..11
    const int li  = ntg >> 2;                      // which linear 0..2
    const int nt  = ntg & 3;
    const int bn0 = mt * 32;
    const int c0  = nt * 128;

    const float* bias  = li == 0 ? bi0 : li == 1 ? bi1 : bi2;
    const float* gamma = li == 0 ? ga0 : li == 1 ? ga1 : ga2;
    const float* beta  = li == 0 ? be0 : li == 1 ? be1 : be2;
    const float* mean  = li == 0 ? mu0 : li == 1 ? mu1 : mu2;
    const float* var   = li == 0 ? va0 : li == 1 ? va1 : va2;
    u16* outp = li == 0 ? oq : li == 1 ? ok : ov;

    const size_t WSZ = (size_t)C_ * C_;
    const u16* w1t = wt_base + (size_t)(2 * li) * WSZ;
    const u16* w2t = wt_base + (size_t)(2 * li + 1) * WSZ;

    const int tid = threadIdx.x;
    const int wv  = tid >> 6, lane = tid & 63;
    const int l15 = lane & 15, g = (lane >> 4) & 3;
    const int wr  = wv >> 1, wc = wv & 1;          // 2x2 wave grid, wave 64x64
    const int go  = wv * 2048 + lane * 16;
    const int lo  = wv * 2048;

    f32x4 accA[4][4], accB[4][4];
    #pragma unroll
    for (int rt = 0; rt < 4; ++rt)
        #pragma unroll
        for (int ct = 0; ct < 4; ++ct) { accA[rt][ct] = {0,0,0,0}; accB[rt][ct] = {0,0,0,0}; }

    const size_t abase = (size_t)mt * 16, bbase = (size_t)nt * 16;

    auto stage = [&](int buf, int kb) {            // 8 gload16 / thread
        char* L = (char*)&lds[buf][0][0];
        const char* ga1p = (const char*)(a1t + ((abase + kb) << 12)) + go;
        const char* ga2p = (const char*)(a2t + ((abase + kb) << 12)) + go;
        const char* gb1 = (const char*)(w1t + ((bbase + kb) << 12)) + go;
        const char* gb2 = (const char*)(w2t + ((bbase + kb) << 12)) + go;
        gload16(ga1p,        L + lo);
        gload16(ga1p + 1024, L + lo + 1024);
        gload16(ga2p,        L + 8192 + lo);
        gload16(ga2p + 1024, L + 8192 + lo + 1024);
        gload16(gb1,        L + 16384 + lo);
        gload16(gb1 + 1024, L + 16384 + lo + 1024);
        gload16(gb2,        L + 24576 + lo);
        gload16(gb2 + 1024, L + 24576 + lo + 1024);
    };

    stage(0, 0);
    __syncthreads();

    #pragma unroll 1
    for (int kb = 0; kb < 16; ++kb) {
        const int buf = kb & 1;
        if (kb < 15) stage(buf ^ 1, kb + 1);       // async, flies under MFMAs
        const char* L = (const char*)&lds[buf][0][0];
        f16x8 a1[4], a2[4];
        #pragma unroll
        for (int rt = 0; rt < 4; ++rt) {
            const int rr = 64 * wr + 16 * rt + l15;
            a1[rt] = *reinterpret_cast<const f16x8*>(L + swz(rr, g));
            a2[rt] = *reinterpret_cast<const f16x8*>(L + 8192 + swz(rr, g));
        }
        #pragma unroll
        for (int ct = 0; ct < 4; ++ct) {
            const int rr2 = 64 * wc + 16 * ct + l15;
            const f16x8 b1 = *reinterpret_cast<const f16x8*>(L + 16384 + swz(rr2, g));
            const f16x8 b2 = *reinterpret_cast<const f16x8*>(L + 24576 + swz(rr2, g));
            #pragma unroll
            for (int rt = 0; rt < 4; ++rt) {
                accA[rt][ct] = __builtin_amdgcn_mfma_f32_16x16x32_f16(a1[rt], b1, accA[rt][ct], 0, 0, 0);
                accB[rt][ct] = __builtin_amdgcn_mfma_f32_16x16x32_f16(a2[rt], b1, accB[rt][ct], 0, 0, 0);
                accB[rt][ct] = __builtin_amdgcn_mfma_f32_16x16x32_f16(a1[rt], b2, accB[rt][ct], 0, 0, 0);
            }
        }
        __syncthreads();   // drains stage loads + everyone's reads
    }

    // epilogue: reconstruct -> bias -> BN -> LIF(v_th=1) over reg r==t
    #pragma unroll
    for (int ct = 0; ct < 4; ++ct) {
        const int c = c0 + 64 * wc + 16 * ct + l15;
        const float rs = 1.0f / sqrtf(var[c] + 1e-5f);
        const float ga = gamma[c], be = beta[c], mu = mean[c], bi = bias[c];
        #pragma unroll
        for (int rt = 0; rt < 4; ++rt) {
            const int bn = bn0 + 16 * wr + 4 * rt + g;
            float vm = 0.f;
            #pragma unroll
            for (int r = 0; r < 4; ++r) {
                const float y = accA[rt][ct][r] + accB[rt][ct][r] * (1.0f / 2048.0f) + bi;
                const float ybn = (y - mu) * rs * ga + be;
                const float h = vm + (ybn - vm) * 0.5f;
                const bool sp = (h >= 1.0f);
                vm = sp ? 0.f : h;
                const int b = bn >> 9, n = bn & 511;
                const int hh = c >> 6, d2 = c & 63;
                outp[((((size_t)r * B_ + b) * H_ + hh) * N_ + n) * D_ + d2] = sp ? 0x3F80 : 0;
            }
        }
    }
}

// ---------------------------------------------------------------------------
// Final split-fp16 MFMA Linear (spike fp16 input, 2 terms) -> BN -> LIF,
// fp32 0/1 out. NOW the qkv shell minus A2: 1024 blocks, 128x128 tile,
// 2x2 waves, 2-buffer 48KB LDS (2+ blocks/CU), 16x16x32. Accumulation order
// per (rt,ct) identical to all passing versions -> bit-identical output.
// ---------------------------------------------------------------------------
__global__ __launch_bounds__(256, 2) void k_linear_out(
    const u16* __restrict__ a1t,
    const u16* __restrict__ w1t, const u16* __restrict__ w2t,
    const float* __restrict__ bias, const float* __restrict__ gamma,
    const float* __restrict__ beta, const float* __restrict__ mean,
    const float* __restrict__ var, float* __restrict__ outp)
{
    __shared__ u16 lds[2][3][4096];   // [buf][A1,B1,B2] = 48KB

    const int dd  = blockIdx.x;                   // 0..1023
    const int lid = (dd & 7) * 128 + (dd >> 3);   // XCD swizzle (bijective)
    const int mt  = lid >> 2;                     // 0..255
    const int nt  = lid & 3;
    const int bn0 = mt * 32;
    const int c0  = nt * 128;

    const int tid = threadIdx.x;
    const int wv  = tid >> 6, lane = tid & 63;
    const int l15 = lane & 15, g = (lane >> 4) & 3;
    const int wr  = wv >> 1, wc = wv & 1;
    const int go  = wv * 2048 + lane * 16;
    const int lo  = wv * 2048;

    f32x4 accA[4][4], accB[4][4];
    #pragma unroll
    for (int rt = 0; rt < 4; ++rt)
        #pragma unroll
        for (int ct = 0; ct < 4; ++ct) { accA[rt][ct] = {0,0,0,0}; accB[rt][ct] = {0,0,0,0}; }

    const size_t abase = (size_t)mt * 16, bbase = (size_t)nt * 16;

    auto stage = [&](int buf, int kb) {           // 6 gload16 / thread
        char* L = (char*)&lds[buf][0][0];
        const char* ga1 = (const char*)(a1t + ((abase + kb) << 12)) + go;
        const char* gb1 = (const char*)(w1t + ((bbase + kb) << 12)) + go;
        const char* gb2 = (const char*)(w2t + ((bbase + kb) << 12)) + go;
        gload16(ga1,        L + lo);
        gload16(ga1 + 1024, L + lo + 1024);
        gload16(gb1,        L + 8192 + lo);
        gload16(gb1 + 1024, L + 8192 + lo + 1024);
        gload16(gb2,        L + 16384 + lo);
        gload16(gb2 + 1024, L + 16384 + lo + 1024);
    };

    stage(0, 0);
    __syncthreads();

    #pragma unroll 1
    for (int kb = 0; kb < 16; ++kb) {
        const int buf = kb & 1;
        if (kb < 15) stage(buf ^ 1, kb + 1);
        const char* L = (const char*)&lds[buf][0][0];
        f16x8 a1[4];
        #pragma unroll
        for (int rt = 0; rt < 4; ++rt) {
            const int rr = 64 * wr + 16 * rt + l15;
            a1[rt] = *reinterpret_cast<const f16x8*>(L + swz(rr, g));
        }
        #pragma unroll
        for (int ct = 0; ct < 4; ++ct) {
            const int rr2 = 64 * wc + 16 * ct + l15;
            const f16x8 b1 = *reinterpret_cast<const f16x8*>(L + 8192 + swz(rr2, g));
            const f16x8 b2 = *reinterpret_cast<const f16x8*>(L + 16384 + swz(rr2, g));
            #pragma unroll
            for (int rt = 0; rt < 4; ++rt) {
                accA[rt][ct] = __builtin_amdgcn_mfma_f32_16x16x32_f16(a1[rt], b1, accA[rt][ct], 0, 0, 0);
                accB[rt][ct] = __builtin_amdgcn_mfma_f32_16x16x32_f16(a1[rt], b2, accB[rt][ct], 0, 0, 0);
            }
        }
        __syncthreads();
    }

    #pragma unroll
    for (int ct = 0; ct < 4; ++ct) {
        const int c = c0 + 64 * wc + 16 * ct + l15;
        const float rs = 1.0f / sqrtf(var[c] + 1e-5f);
        const float ga = gamma[c], be = beta[c], mu = mean[c], bi = bias[c];
        #pragma unroll
        for (int rt = 0; rt < 4; ++rt) {
            const int bn = bn0 + 16 * wr + 4 * rt + g;
            float vm = 0.f;
            #pragma unroll
            for (int r = 0; r < 4; ++r) {
                const float y = accA[rt][ct][r] + accB[rt][ct][r] * (1.0f / 2048.0f) + bi;
                const float ybn = (y - mu) * rs * ga + be;
                const float h = vm + (ybn - vm) * 0.5f;
                const bool sp = (h >= 1.0f);
                vm = sp ? 0.f : h;
                outp[((size_t)r * BN_T + bn) * C_ + c] = sp ? 1.0f : 0.0f;
            }
        }
    }
}

// ---------------------------------------------------------------------------
// MFMA attention + LIF(0.5), whole-KV-in-LDS (round 8) + T14 t+1 register
// prefetch: global loads for the NEXT t issued right after the staging
// barrier, so they land under the long compute phase; ds_write moved to the
// top of the next iteration (loop-top barrier fences WAR). Named, statically
// indexed prefetch buffers (rule 20). MFMA/LIF code untouched -> exact.
// ---------------------------------------------------------------------------
__global__ __launch_bounds__(512, 2) void k_attn_mfma(
    const u16* __restrict__ qg, const u16* __restrict__ kg,
    const u16* __restrict__ vg, u16* __restrict__ s2t)
{
    __shared__ u16 kf[8][4096];    // full K  [jt][SW(kv,d)]   64KB
    __shared__ u16 vf[8][4096];    // full V^T [jt][SW(d,kv)]  64KB
    __shared__ u16 ssb[8][1024];   // per-wave S strip (16x64) 16KB

    const int id  = blockIdx.x;                 // 0..511
    const int lid = (id & 7) * 64 + (id >> 3);  // XCD swizzle; qt-siblings same XCD
    const int bh  = lid >> 2;                   // 0..127
    const int qt  = lid & 3;                    // 128-row q tile
    const int b   = bh >> 3, hh = bh & 7;

    const int tid  = threadIdx.x;
    const int w    = tid >> 6, lane = tid & 63;
    const int l15  = lane & 15, g = lane >> 4;

    const int vkv = (tid & 15) * 4;
    const int vd  = ((tid >> 4) & 15) * 4;

    u16x8  kpre[8];          // prefetched K rows (+32 VGPR)
    ushort4 vpre[4][4];      // prefetched V rows, [slot][row] (+32 VGPR)
    bf16x8 qpre[2], qa[2];
    f32x4 vmem[4], oacc[4];
    #pragma unroll
    for (int d0 = 0; d0 < 4; ++d0) { vmem[d0] = {0,0,0,0}; oacc[d0] = {0,0,0,0}; }

    auto prefetch = [&](int t2) {
        const size_t base2 = ((size_t)t2 * (B_ * H_) + bh) * (size_t)(N_ * D_);
        const u16* kb = kg + base2;
        #pragma unroll
        for (int i = 0; i < 8; ++i)
            kpre[i] = *reinterpret_cast<const u16x8*>(kb + ((size_t)(tid + 512 * i)) * 8);
        const u16* vb = vg + base2;
        #pragma unroll
        for (int i = 0; i < 4; ++i) {
            const int jt = 2 * i + (tid >> 8);
            const int m0 = jt * 64;
            #pragma unroll
            for (int r = 0; r < 4; ++r)
                vpre[i][r] = *reinterpret_cast<const ushort4*>(vb + (size_t)(m0 + vkv + r) * D_ + vd);
        }
        const size_t qrow = base2 + (size_t)(qt * 128 + 16 * w + l15) * D_;
        qpre[0] = *reinterpret_cast<const bf16x8*>(qg + qrow + 8 * g);
        qpre[1] = *reinterpret_cast<const bf16x8*>(qg + qrow + 32 + 8 * g);
    };

    prefetch(0);

    #pragma unroll 1
    for (int t = 0; t < T_; ++t) {
        if (t > 0) __syncthreads();            // readers of t-1 done (WAR fence)
        qa[0] = qpre[0]; qa[1] = qpre[1];

        // ds_write prefetched K (addresses identical to verified round 8)
        #pragma unroll
        for (int i = 0; i < 8; ++i) {
            const int r64 = tid >> 3;
            const int col = (tid & 7) * 8;
            *reinterpret_cast<u16x8*>(&kf[i][SW(r64, col)]) = kpre[i];
        }
        // ds_write prefetched V with 4x4 register transpose
        #pragma unroll
        for (int i = 0; i < 4; ++i) {
            const int jt = 2 * i + (tid >> 8);
            ushort4 wv4;
            wv4.x = vpre[i][0].x; wv4.y = vpre[i][1].x; wv4.z = vpre[i][2].x; wv4.w = vpre[i][3].x;
            *reinterpret_cast<ushort4*>(&vf[jt][SW(vd + 0, vkv)]) = wv4;
            wv4.x = vpre[i][0].y; wv4.y = vpre[i][1].y; wv4.z = vpre[i][2].y; wv4.w = vpre[i][3].y;
            *reinterpret_cast<ushort4*>(&vf[jt][SW(vd + 1, vkv)]) = wv4;
            wv4.x = vpre[i][0].z; wv4.y = vpre[i][1].z; wv4.z = vpre[i][2].z; wv4.w = vpre[i][3].z;
            *reinterpret_cast<ushort4*>(&vf[jt][SW(vd + 2, vkv)]) = wv4;
            wv4.x = vpre[i][0].w; wv4.y = vpre[i][1].w; wv4.z = vpre[i][2].w; wv4.w = vpre[i][3].w;
            *reinterpret_cast<ushort4*>(&vf[jt][SW(vd + 3, vkv)]) = wv4;
        }
        __syncthreads();                        // staged K/V visible

        if (t < 3) prefetch(t + 1);             // lands under the MFMAs below

        u16* sb = &ssb[w][0];
        #pragma unroll
        for (int jt = 0; jt < 8; ++jt) {
            __builtin_amdgcn_s_setprio(1);
            #pragma unroll
            for (int kvt = 0; kvt < 2; ++kvt) {
                f32x4 acc = {0.f, 0.f, 0.f, 0.f};
                #pragma unroll
                for (int c = 0; c < 2; ++c) {
                    const bf16x8 kb = *reinterpret_cast<const bf16x8*>(
                        &kf[jt][SW(16 * kvt + l15, 32 * c + 8 * g)]);
                    acc = __builtin_amdgcn_mfma_f32_16x16x32_bf16(qa[c], kb, acc, 0, 0, 0);
                }
                #pragma unroll
                for (int r = 0; r < 4; ++r)
                    sb[SW(4 * g + r, 16 * kvt + l15)] = f2bf_exact(acc[r]);
            }
            {
                const bf16x8 sa = *reinterpret_cast<const bf16x8*>(&sb[SW(l15, 8 * g)]);
                #pragma unroll
                for (int d0 = 0; d0 < 4; ++d0) {
                    const bf16x8 vb2 = *reinterpret_cast<const bf16x8*>(
                        &vf[jt][SW(16 * d0 + l15, 8 * g)]);
                    oacc[d0] = __builtin_amdgcn_mfma_f32_16x16x32_bf16(sa, vb2, oacc[d0], 0, 0, 0);
                }
            }
            #pragma unroll
            for (int kvt = 2; kvt < 4; ++kvt) {
                f32x4 acc = {0.f, 0.f, 0.f, 0.f};
                #pragma unroll
                for (int c = 0; c < 2; ++c) {
                    const bf16x8 kb = *reinterpret_cast<const bf16x8*>(
                        &kf[jt][SW(16 * kvt + l15, 32 * c + 8 * g)]);
                    acc = __builtin_amdgcn_mfma_f32_16x16x32_bf16(qa[c], kb, acc, 0, 0, 0);
                }
                #pragma unroll
                for (int r = 0; r < 4; ++r)
                    sb[SW(4 * g + r, 16 * kvt + l15)] = f2bf_exact(acc[r]);
            }
            {
                const bf16x8 sa = *reinterpret_cast<const bf16x8*>(&sb[SW(l15, 32 + 8 * g)]);
                #pragma unroll
                for (int d0 = 0; d0 < 4; ++d0) {
                    const bf16x8 vb2 = *reinterpret_cast<const bf16x8*>(
                        &vf[jt][SW(16 * d0 + l15, 32 + 8 * g)]);
                    oacc[d0] = __builtin_amdgcn_mfma_f32_16x16x32_bf16(sa, vb2, oacc[d0], 0, 0, 0);
                }
            }
            __builtin_amdgcn_s_setprio(0);
        }

        // LIF (v_th=0.5); 0.125 folded here (pow2, exact); tiled s2t out
        #pragma unroll
        for (int d0 = 0; d0 < 4; ++d0) {
            const int c = hh * 64 + d0 * 16 + l15;
            const int kb2 = c >> 5, kq = (c >> 3) & 3, e = c & 7;
            #pragma unroll
            for (int r = 0; r < 4; ++r) {
                const float o = oacc[d0][r] * 0.125f;
                const float h = vmem[d0][r] + (o - vmem[d0][r]) * 0.5f;
                const bool sp = (h >= 0.5f);
                vmem[d0][r] = sp ? 0.f : h;
                const int n = qt * 128 + 16 * w + 4 * g + r;
                const int bn = b * 512 + n;
                const int mt2 = bn >> 5;
                const int rr2 = (bn & 31) * 4 + t;
                const size_t off = (((size_t)mt2 * 16 + kb2) << 13) + (rr2 << 6)
                                 + (((kq ^ ((rr2 >> 1) & 3)) & 3) << 4) + (e << 1);
                *(u16*)((char*)s2t + off) = sp ? 0x3C00 : 0;   // fp16 1.0
            }
            oacc[d0] = {0.f, 0.f, 0.f, 0.f};
        }
    }
}

extern "C" void kernel_launch(void* const* d_in, const int* in_sizes, int n_in,
                              void* d_out, int out_size, void* d_ws, size_t ws_size,
                              hipStream_t stream)
{
    const float* x = (const float*)d_in[0];
    const float* W[4]  = {(const float*)d_in[1],  (const float*)d_in[7],  (const float*)d_in[13], (const float*)d_in[19]};
    const float* Bi[4] = {(const float*)d_in[2],  (const float*)d_in[8],  (const float*)d_in[14], (const float*)d_in[20]};
    const float* Ga[4] = {(const float*)d_in[3],  (const float*)d_in[9],  (const float*)d_in[15], (const float*)d_in[21]};
    const float* Be[4] = {(const float*)d_in[4],  (const float*)d_in[10], (const float*)d_in[16], (const float*)d_in[22]};
    const float* Mu[4] = {(const float*)d_in[5],  (const float*)d_in[11], (const float*)d_in[17], (const float*)d_in[23]};
    const float* Va[4] = {(const float*)d_in[6],  (const float*)d_in[12], (const float*)d_in[18], (const float*)d_in[24]};

    const size_t SPK = (size_t)T_ * B_ * N_ * C_;   // 16,777,216
    const size_t WSZ = (size_t)C_ * C_;             // 262,144
    u16* qb  = (u16*)d_ws;          // bf16 spikes [T,B,H,N,D]
    u16* kbf = qb + SPK;
    u16* vbf = kbf + SPK;
    u16* x1t = vbf + SPK;           // tiled x1; reused as s2t after linears
    u16* x2t = x1t + SPK;           // tiled x2
    u16* wt  = x2t + SPK;           // 4 weights x 2 splits x WSZ
    u16* s2t = x1t;                 // attn output overlays x1t (dead by then)

    dim3 blk(256);
    k_split_all<<<4352, blk, 0, stream>>>(x, W[0], W[1], W[2], W[3], x1t, x2t, wt);

    k_linear_qkv<<<3072, blk, 0, stream>>>(x1t, x2t, wt,
        Bi[0], Ga[0], Be[0], Mu[0], Va[0],
        Bi[1], Ga[1], Be[1], Mu[1], Va[1],
        Bi[2], Ga[2], Be[2], Mu[2], Va[2],
        qb, kbf, vbf);
    k_attn_mfma<<<512, dim3(512), 0, stream>>>(qb, kbf, vbf, s2t);
    k_linear_out<<<1024, blk, 0, stream>>>(s2t, wt + 6*WSZ, wt + 7*WSZ,
        Bi[3], Ga[3], Be[3], Mu[3], Va[3], (float*)d_out);
}